// Round 6
// baseline (544.159 us; speedup 1.0000x reference)
//
#include <hip/hip_runtime.h>
#include <math.h>
#include <stdint.h>

#define B_ 32
#define P_ 512
#define N_ 1024
#define E_ 128
#define H_ 8
#define D_ 16
#define BHP_ (B_ * H_ * P_)   // 131072

typedef unsigned short ushort_t;
typedef __attribute__((ext_vector_type(8))) short short8;
typedef __attribute__((ext_vector_type(4))) float f32x4;

union U8 { short8 s8; uint32_t u[4]; };

__device__ __forceinline__ void fma4(float4& acc, float a, float4 w) {
  acc.x = fmaf(a, w.x, acc.x); acc.y = fmaf(a, w.y, acc.y);
  acc.z = fmaf(a, w.z, acc.z); acc.w = fmaf(a, w.w, acc.w);
}
__device__ __forceinline__ float fast_tanh(float x) {
  x = fminf(20.f, fmaxf(-20.f, x));
  float e = __expf(2.f * x);
  return (e - 1.f) / (e + 1.f);
}
// float -> interleaved (hi bf16 | lo bf16) dword; lo = exact residual truncated
__device__ __forceinline__ uint32_t f32_to_hl(float x) {
  uint32_t bits = __float_as_uint(x);
  uint32_t hi = bits >> 16;
  float rem = x - __uint_as_float(bits & 0xFFFF0000u);
  uint32_t lo = __float_as_uint(rem) >> 16;
  return hi | (lo << 16);
}

// ---------------------------------------------------------------------------
// Fused K/V projection, 64-row tiles (512 blocks -> 2-3 blocks/CU).
// khl:  [B*N][256]  (hi,lo) interleaved along d (all 8 heads: 2*col)
// vthl: [B*H*16][2048] V transposed per head: row=(b*8+h)*16+d, el=2*n+part
// ---------------------------------------------------------------------------
__global__ __launch_bounds__(256, 3) void gemm_kv(
    const float* __restrict__ A, const float* __restrict__ Wk,
    const float* __restrict__ Wv, ushort_t* __restrict__ khl,
    ushort_t* __restrict__ vthl) {
  __shared__ float As[64][33];
  __shared__ float Wks[32][128];
  __shared__ float Wvs[32][128];
  const int tid = threadIdx.x;
  const size_t m0 = (size_t)blockIdx.x * 64;
  const int tr = tid >> 3, tc = tid & 7;
  const int r0 = tr * 2;
  const int c0 = tc * 16;

  float4 acck[2][4], accv[2][4];
#pragma unroll
  for (int j = 0; j < 2; ++j)
#pragma unroll
    for (int i = 0; i < 4; ++i) {
      acck[j][i] = make_float4(0.f, 0.f, 0.f, 0.f);
      accv[j][i] = make_float4(0.f, 0.f, 0.f, 0.f);
    }

  for (int kb = 0; kb < 4; ++kb) {
    __syncthreads();
    {
      int idx = tid;
#pragma unroll
      for (int it = 0; it < 2; ++it, idx += 256) {
        int r = idx >> 3, k4 = idx & 7;
        float4 v = reinterpret_cast<const float4*>(A + (m0 + r) * 128 + kb * 32)[k4];
        As[r][k4 * 4 + 0] = v.x; As[r][k4 * 4 + 1] = v.y;
        As[r][k4 * 4 + 2] = v.z; As[r][k4 * 4 + 3] = v.w;
      }
      idx = tid;
#pragma unroll
      for (int it = 0; it < 4; ++it, idx += 256) {
        int kk = idx >> 5, c4 = idx & 31;
        reinterpret_cast<float4*>(&Wks[kk][0])[c4] =
            reinterpret_cast<const float4*>(Wk + (size_t)(kb * 32 + kk) * 128)[c4];
      }
      idx = tid;
#pragma unroll
      for (int it = 0; it < 4; ++it, idx += 256) {
        int kk = idx >> 5, c4 = idx & 31;
        reinterpret_cast<float4*>(&Wvs[kk][0])[c4] =
            reinterpret_cast<const float4*>(Wv + (size_t)(kb * 32 + kk) * 128)[c4];
      }
    }
    __syncthreads();
#pragma unroll 8
    for (int kk = 0; kk < 32; ++kk) {
      float a0 = As[r0 + 0][kk], a1 = As[r0 + 1][kk];
      const float4* wkr = reinterpret_cast<const float4*>(&Wks[kk][c0]);
      const float4* wvr = reinterpret_cast<const float4*>(&Wvs[kk][c0]);
#pragma unroll
      for (int i = 0; i < 4; ++i) {
        float4 wk = wkr[i], wv = wvr[i];
        fma4(acck[0][i], a0, wk); fma4(acck[1][i], a1, wk);
        fma4(accv[0][i], a0, wv); fma4(accv[1][i], a1, wv);
      }
    }
  }

  // K epilogue: interleaved hi/lo bf16
#pragma unroll
  for (int j = 0; j < 2; ++j) {
    ushort_t* krow = khl + (m0 + r0 + j) * 256;
#pragma unroll
    for (int i = 0; i < 4; ++i) {
      uint4 pk;
      pk.x = f32_to_hl(acck[j][i].x);
      pk.y = f32_to_hl(acck[j][i].y);
      pk.z = f32_to_hl(acck[j][i].z);
      pk.w = f32_to_hl(acck[j][i].w);
      *reinterpret_cast<uint4*>(krow + 2 * (c0 + 4 * i)) = pk;
    }
  }
  // V epilogue: per-head transposed, interleaved hi/lo along n (2 n per store)
  const int bb = (int)(m0 >> 10);
  const int nbase = (int)(m0 & 1023) + r0;
#pragma unroll
  for (int i = 0; i < 4; ++i) {
#pragma unroll
    for (int e = 0; e < 4; ++e) {
      const int c = c0 + 4 * i + e;
      const int hh = c >> 4, dd = c & 15;
      uint2 pv;
      pv.x = f32_to_hl(reinterpret_cast<const float*>(&accv[0][i])[e]);
      pv.y = f32_to_hl(reinterpret_cast<const float*>(&accv[1][i])[e]);
      *reinterpret_cast<uint2*>(
          vthl + (size_t)((bb * H_ + hh) * 16 + dd) * 2048 + 2 * nbase) = pv;
    }
  }
}

// ---------------------------------------------------------------------------
// Q projection, 32-row tiles (512 blocks): q = [eln|load] @ Wq -> hl bf16
// ---------------------------------------------------------------------------
__global__ __launch_bounds__(256, 4) void gemm_q32(
    const float* __restrict__ A, const float* __restrict__ W,
    const float* __restrict__ ea, const float* __restrict__ ew,
    ushort_t* __restrict__ qhl) {
  __shared__ float As[32][33];
  __shared__ float Ws[32][128];
  const int tid = threadIdx.x;
  const size_t m0 = (size_t)blockIdx.x * 32;
  const int r0 = tid >> 3;
  const int c0 = (tid & 7) * 16;

  float4 acc[4];
#pragma unroll
  for (int i = 0; i < 4; ++i) acc[i] = make_float4(0.f, 0.f, 0.f, 0.f);

  for (int kb = 0; kb < 4; ++kb) {
    __syncthreads();
    {
      int r = tid >> 3, k4 = tid & 7;
      float4 v = reinterpret_cast<const float4*>(A + (m0 + r) * 128 + kb * 32)[k4];
      As[r][k4 * 4 + 0] = v.x; As[r][k4 * 4 + 1] = v.y;
      As[r][k4 * 4 + 2] = v.z; As[r][k4 * 4 + 3] = v.w;
      int idx = tid;
#pragma unroll
      for (int it = 0; it < 4; ++it, idx += 256) {
        int kk = idx >> 5, c4 = idx & 31;
        reinterpret_cast<float4*>(&Ws[kk][0])[c4] =
            reinterpret_cast<const float4*>(W + (size_t)(kb * 32 + kk) * 128)[c4];
      }
    }
    __syncthreads();
#pragma unroll 8
    for (int kk = 0; kk < 32; ++kk) {
      float a0 = As[r0][kk];
      const float4* wr = reinterpret_cast<const float4*>(&Ws[kk][c0]);
      fma4(acc[0], a0, wr[0]); fma4(acc[1], a0, wr[1]);
      fma4(acc[2], a0, wr[2]); fma4(acc[3], a0, wr[3]);
    }
  }
  {
    const float4* ew4 = reinterpret_cast<const float4*>(ew + c0);
    float av = ea[m0 + r0];
    fma4(acc[0], av, ew4[0]); fma4(acc[1], av, ew4[1]);
    fma4(acc[2], av, ew4[2]); fma4(acc[3], av, ew4[3]);
  }
  ushort_t* qrow = qhl + (m0 + r0) * 256;
#pragma unroll
  for (int i = 0; i < 4; ++i) {
    uint4 pq;
    pq.x = f32_to_hl(acc[i].x); pq.y = f32_to_hl(acc[i].y);
    pq.z = f32_to_hl(acc[i].z); pq.w = f32_to_hl(acc[i].w);
    *reinterpret_cast<uint4*>(qrow + 2 * (c0 + 4 * i)) = pq;
  }
}

// ---------------------------------------------------------------------------
// Wc projection, 32-row tiles (512 blocks): C = A @ W + bias (fp32)
// ---------------------------------------------------------------------------
__global__ __launch_bounds__(256, 4) void gemm_c32(
    const float* __restrict__ A, const float* __restrict__ W,
    const float* __restrict__ bias, float* __restrict__ C) {
  __shared__ float As[32][33];
  __shared__ float Ws[32][128];
  const int tid = threadIdx.x;
  const size_t m0 = (size_t)blockIdx.x * 32;
  const int r0 = tid >> 3;
  const int c0 = (tid & 7) * 16;

  float4 acc[4];
#pragma unroll
  for (int i = 0; i < 4; ++i) acc[i] = make_float4(0.f, 0.f, 0.f, 0.f);

  for (int kb = 0; kb < 4; ++kb) {
    __syncthreads();
    {
      int r = tid >> 3, k4 = tid & 7;
      float4 v = reinterpret_cast<const float4*>(A + (m0 + r) * 128 + kb * 32)[k4];
      As[r][k4 * 4 + 0] = v.x; As[r][k4 * 4 + 1] = v.y;
      As[r][k4 * 4 + 2] = v.z; As[r][k4 * 4 + 3] = v.w;
      int idx = tid;
#pragma unroll
      for (int it = 0; it < 4; ++it, idx += 256) {
        int kk = idx >> 5, c4 = idx & 31;
        reinterpret_cast<float4*>(&Ws[kk][0])[c4] =
            reinterpret_cast<const float4*>(W + (size_t)(kb * 32 + kk) * 128)[c4];
      }
    }
    __syncthreads();
#pragma unroll 8
    for (int kk = 0; kk < 32; ++kk) {
      float a0 = As[r0][kk];
      const float4* wr = reinterpret_cast<const float4*>(&Ws[kk][c0]);
      fma4(acc[0], a0, wr[0]); fma4(acc[1], a0, wr[1]);
      fma4(acc[2], a0, wr[2]); fma4(acc[3], a0, wr[3]);
    }
  }
  const float4* b4 = reinterpret_cast<const float4*>(bias + c0);
  float4* c4p = reinterpret_cast<float4*>(C + (m0 + r0) * 128 + c0);
#pragma unroll
  for (int i = 0; i < 4; ++i) {
    float4 bv = b4[i];
    float4 o = acc[i];
    o.x += bv.x; o.y += bv.y; o.z += bv.z; o.w += bv.w;
    c4p[i] = o;
  }
}

// ---------------------------------------------------------------------------
// Flash-decode MFMA attention pass: N split x2, ILP2 p-tiles per wave.
// Grid (8 = 4 ptiles x 2 nsplit, H, B), 4 waves. Writes unnormalized
// partials (o, m, l) per (ns, b, h, p).
// ---------------------------------------------------------------------------
__global__ __launch_bounds__(256, 8) void attn_pass(
    const ushort_t* __restrict__ qhl, const ushort_t* __restrict__ khl,
    const ushort_t* __restrict__ vthl, const float* __restrict__ mask,
    float* __restrict__ pout, float* __restrict__ pml) {
  const int b = blockIdx.z, h = blockIdx.y;
  const int pt = blockIdx.x >> 1;
  const int ns = blockIdx.x & 1;
  const int tid = threadIdx.x;
  const int w = tid >> 6, lane = tid & 63;
  const int lp = lane & 15, g = lane >> 4;
  const int pA = pt * 128 + w * 16 + lp;
  const int pB = pA + 64;

  __shared__ __align__(16) ushort_t Ks[64 * 40];    // row stride 40 el (80 B)
  __shared__ __align__(16) ushort_t VTs[16 * 136];  // row stride 136 el (272 B)

  // Q fragments for both p-tiles: B1 = (qh,qh) pairs, B2 = (ql,0) pairs
  U8 qA1u, qA2u, qB1u, qB2u;
  {
    uint4 qldA = *reinterpret_cast<const uint4*>(
        qhl + (size_t)(b * P_ + pA) * 256 + h * 32 + g * 8);
    uint4 qldB = *reinterpret_cast<const uint4*>(
        qhl + (size_t)(b * P_ + pB) * 256 + h * 32 + g * 8);
    uint32_t a[4] = {qldA.x, qldA.y, qldA.z, qldA.w};
    uint32_t c[4] = {qldB.x, qldB.y, qldB.z, qldB.w};
#pragma unroll
    for (int i = 0; i < 4; ++i) {
      uint32_t lo16 = a[i] & 0xFFFFu;
      qA1u.u[i] = lo16 | (lo16 << 16);
      qA2u.u[i] = a[i] >> 16;
      uint32_t lo16b = c[i] & 0xFFFFu;
      qB1u.u[i] = lo16b | (lo16b << 16);
      qB2u.u[i] = c[i] >> 16;
    }
  }
  const short8 qA1 = qA1u.s8, qA2 = qA2u.s8, qB1 = qB1u.s8, qB2 = qB2u.s8;

  const float* mrowA = mask + (size_t)(b * P_ + pA) * N_;
  const float* mrowB = mask + (size_t)(b * P_ + pB) * N_;

  f32x4 accA = {0.f, 0.f, 0.f, 0.f}, accB = {0.f, 0.f, 0.f, 0.f};
  float mA = -1e30f, lA = 0.f, mB = -1e30f, lB = 0.f;

  for (int ch = 0; ch < 8; ++ch) {
    const int n0 = ns * 512 + ch * 64;
    __syncthreads();
    {
      const int n = tid >> 2, seg = tid & 3;
      uint4 kv = *reinterpret_cast<const uint4*>(
          khl + (size_t)(b * N_ + n0 + n) * 256 + h * 32 + seg * 8);
      *reinterpret_cast<uint4*>(Ks + n * 40 + seg * 8) = kv;
      const int d = tid >> 4, s2 = tid & 15;
      uint4 vv = *reinterpret_cast<const uint4*>(
          vthl + (size_t)((b * H_ + h) * 16 + d) * 2048 + n0 * 2 + s2 * 8);
      *reinterpret_cast<uint4*>(VTs + d * 136 + s2 * 8) = vv;
    }
    __syncthreads();

    // scores for both p-tiles; K fragment loaded once, used twice
    float svA[4][4], svB[4][4];
    float cmA = -1e30f, cmB = -1e30f;
#pragma unroll
    for (int tt = 0; tt < 4; ++tt) {
      short8 ka = *reinterpret_cast<const short8*>(Ks + (tt * 16 + lp) * 40 + g * 8);
      f32x4 aA = {0.f, 0.f, 0.f, 0.f};
      aA = __builtin_amdgcn_mfma_f32_16x16x32_bf16(ka, qA1, aA, 0, 0, 0);
      aA = __builtin_amdgcn_mfma_f32_16x16x32_bf16(ka, qA2, aA, 0, 0, 0);
      f32x4 aB = {0.f, 0.f, 0.f, 0.f};
      aB = __builtin_amdgcn_mfma_f32_16x16x32_bf16(ka, qB1, aB, 0, 0, 0);
      aB = __builtin_amdgcn_mfma_f32_16x16x32_bf16(ka, qB2, aB, 0, 0, 0);
      float4 mvA = *reinterpret_cast<const float4*>(mrowA + n0 + tt * 16 + g * 4);
      float4 mvB = *reinterpret_cast<const float4*>(mrowB + n0 + tt * 16 + g * 4);
      svA[tt][0] = fmaf(aA[0], 0.25f, mvA.x);
      svA[tt][1] = fmaf(aA[1], 0.25f, mvA.y);
      svA[tt][2] = fmaf(aA[2], 0.25f, mvA.z);
      svA[tt][3] = fmaf(aA[3], 0.25f, mvA.w);
      svB[tt][0] = fmaf(aB[0], 0.25f, mvB.x);
      svB[tt][1] = fmaf(aB[1], 0.25f, mvB.y);
      svB[tt][2] = fmaf(aB[2], 0.25f, mvB.z);
      svB[tt][3] = fmaf(aB[3], 0.25f, mvB.w);
      cmA = fmaxf(cmA, fmaxf(fmaxf(svA[tt][0], svA[tt][1]), fmaxf(svA[tt][2], svA[tt][3])));
      cmB = fmaxf(cmB, fmaxf(fmaxf(svB[tt][0], svB[tt][1]), fmaxf(svB[tt][2], svB[tt][3])));
    }
    cmA = fmaxf(cmA, __shfl_xor(cmA, 16));
    cmB = fmaxf(cmB, __shfl_xor(cmB, 16));
    cmA = fmaxf(cmA, __shfl_xor(cmA, 32));
    cmB = fmaxf(cmB, __shfl_xor(cmB, 32));
    const float nmA = fmaxf(mA, cmA), nmB = fmaxf(mB, cmB);
    const float fA = __expf(mA - nmA), fB = __expf(mB - nmB);
    accA[0] *= fA; accA[1] *= fA; accA[2] *= fA; accA[3] *= fA;
    accB[0] *= fB; accB[1] *= fB; accB[2] *= fB; accB[3] *= fB;
    float lsA = 0.f, lsB = 0.f;
#pragma unroll
    for (int tt = 0; tt < 4; ++tt)
#pragma unroll
      for (int r = 0; r < 4; ++r) {
        float eA = __expf(svA[tt][r] - nmA);
        float eB = __expf(svB[tt][r] - nmB);
        svA[tt][r] = eA; lsA += eA;
        svB[tt][r] = eB; lsB += eB;
      }
    lsA += __shfl_xor(lsA, 16); lsB += __shfl_xor(lsB, 16);
    lsA += __shfl_xor(lsA, 32); lsB += __shfl_xor(lsB, 32);
    lA = lA * fA + lsA; mA = nmA;
    lB = lB * fB + lsB; mB = nmB;

    // PV for both p-tiles; V fragment loaded once, used twice
#pragma unroll
    for (int tt = 0; tt < 4; ++tt) {
      U8 pA1, pA2, pB1, pB2;
#pragma unroll
      for (int r = 0; r < 4; ++r) {
        uint32_t ba = __float_as_uint(svA[tt][r]);
        uint32_t ha = ba >> 16;
        float rema = svA[tt][r] - __uint_as_float(ba & 0xFFFF0000u);
        pA1.u[r] = ha | (ha << 16);
        pA2.u[r] = __float_as_uint(rema) >> 16;
        uint32_t bb2 = __float_as_uint(svB[tt][r]);
        uint32_t hb = bb2 >> 16;
        float remb = svB[tt][r] - __uint_as_float(bb2 & 0xFFFF0000u);
        pB1.u[r] = hb | (hb << 16);
        pB2.u[r] = __float_as_uint(remb) >> 16;
      }
      short8 va = *reinterpret_cast<const short8*>(VTs + lp * 136 + tt * 32 + g * 8);
      accA = __builtin_amdgcn_mfma_f32_16x16x32_bf16(va, pA1.s8, accA, 0, 0, 0);
      accA = __builtin_amdgcn_mfma_f32_16x16x32_bf16(va, pA2.s8, accA, 0, 0, 0);
      accB = __builtin_amdgcn_mfma_f32_16x16x32_bf16(va, pB1.s8, accB, 0, 0, 0);
      accB = __builtin_amdgcn_mfma_f32_16x16x32_bf16(va, pB2.s8, accB, 0, 0, 0);
    }
  }

  // write unnormalized partials
  const size_t idxA = (size_t)(b * H_ + h) * P_ + pA;
  const size_t idxB = (size_t)(b * H_ + h) * P_ + pB;
  float4 oA, oB;
  oA.x = accA[0]; oA.y = accA[1]; oA.z = accA[2]; oA.w = accA[3];
  oB.x = accB[0]; oB.y = accB[1]; oB.z = accB[2]; oB.w = accB[3];
  *reinterpret_cast<float4*>(pout + ((size_t)ns * BHP_ + idxA) * 16 + g * 4) = oA;
  *reinterpret_cast<float4*>(pout + ((size_t)ns * BHP_ + idxB) * 16 + g * 4) = oB;
  if (g == 0) {
    reinterpret_cast<float2*>(pml)[(size_t)ns * BHP_ + idxA] = make_float2(mA, lA);
    reinterpret_cast<float2*>(pml)[(size_t)ns * BHP_ + idxB] = make_float2(mB, lB);
  }
}

// ---------------------------------------------------------------------------
// Combine 2 partials -> normalized attention output in [B,P,H*D] layout.
// ---------------------------------------------------------------------------
__global__ __launch_bounds__(256, 8) void attn_combine(
    const float* __restrict__ pout, const float* __restrict__ pml,
    float* __restrict__ O) {
  const int idx = blockIdx.x * 256 + threadIdx.x;   // over B*H*P
  const int b = idx >> 12;
  const int h = (idx >> 9) & 7;
  const int p = idx & 511;
  float2 ml0 = reinterpret_cast<const float2*>(pml)[idx];
  float2 ml1 = reinterpret_cast<const float2*>(pml)[BHP_ + idx];
  const float M = fmaxf(ml0.x, ml1.x);
  const float w0 = __expf(ml0.x - M), w1 = __expf(ml1.x - M);
  const float inv = 1.f / (ml0.y * w0 + ml1.y * w1);
  const float4* p0 = reinterpret_cast<const float4*>(pout + (size_t)idx * 16);
  const float4* p1 = reinterpret_cast<const float4*>(pout + ((size_t)BHP_ + idx) * 16);
  float4* o4 = reinterpret_cast<float4*>(O + (size_t)(b * P_ + p) * E_ + h * 16);
#pragma unroll
  for (int i = 0; i < 4; ++i) {
    float4 a = p0[i], c = p1[i];
    float4 o;
    o.x = (a.x * w0 + c.x * w1) * inv;
    o.y = (a.y * w0 + c.y * w1) * inv;
    o.z = (a.z * w0 + c.z * w1) * inv;
    o.w = (a.w * w0 + c.w * w1) * inv;
    o4[i] = o;
  }
}

// ---------------------------------------------------------------------------
// MFMA logits: T[b,p,n] = 10*tanh((mh[b,p,:]·enc[b,n,:])/sqrt(128)) + mask
// Grid (4 n-quarters, 8 p-tiles, B). Block 256 = 4 waves x 16 p.
// ---------------------------------------------------------------------------
__global__ __launch_bounds__(256, 4) void logits_mfma(
    const float* __restrict__ mh, const float* __restrict__ enc,
    const float* __restrict__ mask, float* __restrict__ T) {
  const int b = blockIdx.z;
  const int p0 = blockIdx.y * 64;
  const int nq = blockIdx.x;           // n quarter: 256 cols
  const int tid = threadIdx.x;
  const int w = tid >> 6, lane = tid & 63;
  const int lp = lane & 15, g = lane >> 4;
  const int p = p0 + w * 16 + lp;

  __shared__ __align__(16) ushort_t Es[64 * 264];   // 64 enc rows, hl

  // B fragments: this lane's mh row, 8 k-windows of 16
  U8 fb1[8], fb2[8];
  {
    const float* mrow_mh = mh + (size_t)(b * P_ + p) * E_;
#pragma unroll
    for (int win = 0; win < 8; ++win) {
      float4 v = *reinterpret_cast<const float4*>(mrow_mh + win * 16 + g * 4);
      float vv[4] = {v.x, v.y, v.z, v.w};
#pragma unroll
      for (int r = 0; r < 4; ++r) {
        uint32_t bits = __float_as_uint(vv[r]);
        uint32_t hh = bits >> 16;
        float rem = vv[r] - __uint_as_float(bits & 0xFFFF0000u);
        fb1[win].u[r] = hh | (hh << 16);
        fb2[win].u[r] = __float_as_uint(rem) >> 16;
      }
    }
  }

  const float* mrow = mask + (size_t)(b * P_ + p) * N_ + nq * 256;
  float* trow = T + (size_t)(b * P_ + p) * N_ + nq * 256;
  const float inv_s = 0.08838834764831845f;  // 1/sqrt(128)

  for (int ch = 0; ch < 4; ++ch) {           // 64 n per chunk
    const int n0g = nq * 256 + ch * 64;
    __syncthreads();
    {
      int idx = tid;
#pragma unroll
      for (int it = 0; it < 8; ++it, idx += 256) {
        const int r = idx >> 5, f4 = idx & 31;
        float4 v = *reinterpret_cast<const float4*>(
            enc + ((size_t)b * N_ + n0g + r) * E_ + f4 * 4);
        uint4 o;
        o.x = f32_to_hl(v.x); o.y = f32_to_hl(v.y);
        o.z = f32_to_hl(v.z); o.w = f32_to_hl(v.w);
        *reinterpret_cast<uint4*>(Es + r * 264 + f4 * 8) = o;
      }
    }
    __syncthreads();

#pragma unroll
    for (int tt = 0; tt < 4; ++tt) {
      f32x4 acc = {0.f, 0.f, 0.f, 0.f};
#pragma unroll
      for (int win = 0; win < 8; ++win) {
        short8 ea = *reinterpret_cast<const short8*>(
            Es + (tt * 16 + lp) * 264 + win * 32 + g * 8);
        acc = __builtin_amdgcn_mfma_f32_16x16x32_bf16(ea, fb1[win].s8, acc, 0, 0, 0);
        acc = __builtin_amdgcn_mfma_f32_16x16x32_bf16(ea, fb2[win].s8, acc, 0, 0, 0);
      }
      float4 mv = *reinterpret_cast<const float4*>(mrow + ch * 64 + tt * 16 + g * 4);
      float4 o;
      o.x = fmaf(10.f, fast_tanh(acc[0] * inv_s), mv.x);
      o.y = fmaf(10.f, fast_tanh(acc[1] * inv_s), mv.y);
      o.z = fmaf(10.f, fast_tanh(acc[2] * inv_s), mv.z);
      o.w = fmaf(10.f, fast_tanh(acc[3] * inv_s), mv.w);
      *reinterpret_cast<float4*>(trow + ch * 64 + tt * 16 + g * 4) = o;
    }
  }
}

// ---------------------------------------------------------------------------
// probs[row,:] = softmax(T[row,:] * 10)
// ---------------------------------------------------------------------------
__global__ __launch_bounds__(256, 4) void softmax_rows(
    const float* __restrict__ T, float* __restrict__ O) {
  const size_t row = blockIdx.x;
  const int tid = threadIdx.x;
  const float4 v = reinterpret_cast<const float4*>(T + row * N_)[tid];
  float lm = fmaxf(fmaxf(v.x, v.y), fmaxf(v.z, v.w));
#pragma unroll
  for (int o = 32; o; o >>= 1) lm = fmaxf(lm, __shfl_xor(lm, o));
  __shared__ float red[8];
  const int wave = tid >> 6, lane = tid & 63;
  if (lane == 0) red[wave] = lm;
  __syncthreads();
  const float m = fmaxf(fmaxf(red[0], red[1]), fmaxf(red[2], red[3]));
  float4 w;
  w.x = __expf((v.x - m) * 10.f);
  w.y = __expf((v.y - m) * 10.f);
  w.z = __expf((v.z - m) * 10.f);
  w.w = __expf((v.w - m) * 10.f);
  float ls = w.x + w.y + w.z + w.w;
#pragma unroll
  for (int o = 32; o; o >>= 1) ls += __shfl_xor(ls, o);
  if (lane == 0) red[4 + wave] = ls;
  __syncthreads();
  const float inv = 1.f / (red[4] + red[5] + red[6] + red[7]);
  float4 o4;
  o4.x = w.x * inv; o4.y = w.y * inv; o4.z = w.z * inv; o4.w = w.w * inv;
  reinterpret_cast<float4*>(O + row * N_)[tid] = o4;
}

extern "C" void kernel_launch(void* const* d_in, const int* in_sizes, int n_in,
                              void* d_out, int out_size, void* d_ws, size_t ws_size,
                              hipStream_t stream) {
  const float* eln  = (const float*)d_in[0];
  const float* load = (const float*)d_in[1];
  const float* mask = (const float*)d_in[2];
  const float* enc  = (const float*)d_in[3];
  const float* Wq   = (const float*)d_in[4];
  const float* Wk   = (const float*)d_in[5];
  const float* Wv   = (const float*)d_in[6];
  const float* Wc   = (const float*)d_in[7];
  const float* bc   = (const float*)d_in[8];
  float* out = (float*)d_out;

  // Workspace layout (bytes):
  //   khl  : 16.78 MB   vthl : 16.78 MB   qhl/mhbuf : 8.39 MB
  //   tbuf : 67.11 MB  -- internally: abuf (8.39) | pout2 (16.78) | pml2 (2.1)
  char* base = (char*)d_ws;
  ushort_t* khl  = (ushort_t*)base;
  ushort_t* vthl = (ushort_t*)(base + 16777216);
  ushort_t* qhl  = (ushort_t*)(base + 2 * 16777216);
  float* mhbuf   = (float*)(base + 2 * 16777216);            // overlaps qhl
  float* tbuf    = (float*)(base + 2 * 16777216 + 8388608);
  float* abuf    = tbuf;                                     // dead before logits
  float* pout    = (float*)((char*)tbuf + 8388608);
  float* pml     = (float*)((char*)tbuf + 8388608 + 16777216);

  // K|V projections -> bf16 hi/lo (+ V transpose)
  gemm_kv<<<dim3(512), 256, 0, stream>>>(enc, Wk, Wv, khl, vthl);
  // q = [eln | load] @ Wq_last -> bf16 hi/lo
  gemm_q32<<<dim3(512), 256, 0, stream>>>(eln, Wq, load, Wq + 128 * 128, qhl);
  // flash-decode MFMA attention (N-split x2, ILP2) + combine
  attn_pass<<<dim3(8, H_, B_), 256, 0, stream>>>(qhl, khl, vthl, mask, pout, pml);
  attn_combine<<<dim3(BHP_ / 256), 256, 0, stream>>>(pout, pml, abuf);
  // mh = attn_out @ Wc + bc
  gemm_c32<<<dim3(512), 256, 0, stream>>>(abuf, Wc, bc, mhbuf);
  // logits = 10*tanh(mh·encT/sqrt(128)) + mask
  logits_mfma<<<dim3(4, 8, B_), 256, 0, stream>>>(mhbuf, enc, mask, tbuf);
  // probs = softmax(logits/0.1)
  softmax_rows<<<dim3(16384), 256, 0, stream>>>(tbuf, out);
}

// Round 8
// 366.804 us; speedup vs baseline: 1.4835x; 1.4835x over previous
//
#include <hip/hip_runtime.h>
#include <math.h>
#include <stdint.h>

#define B_ 32
#define P_ 512
#define N_ 1024
#define E_ 128
#define H_ 8
#define D_ 16
#define BHP_ (B_ * H_ * P_)   // 131072

typedef unsigned short ushort_t;
typedef __attribute__((ext_vector_type(8))) short short8;
typedef __attribute__((ext_vector_type(4))) float f32x4;

union U8 { short8 s8; uint32_t u[4]; };

__device__ __forceinline__ void fma4(float4& acc, float a, float4 w) {
  acc.x = fmaf(a, w.x, acc.x); acc.y = fmaf(a, w.y, acc.y);
  acc.z = fmaf(a, w.z, acc.z); acc.w = fmaf(a, w.w, acc.w);
}
__device__ __forceinline__ float fast_tanh(float x) {
  x = fminf(20.f, fmaxf(-20.f, x));
  float e = __expf(2.f * x);
  return (e - 1.f) / (e + 1.f);
}
// float -> interleaved (hi bf16 | lo bf16) dword; lo = exact residual truncated
__device__ __forceinline__ uint32_t f32_to_hl(float x) {
  uint32_t bits = __float_as_uint(x);
  uint32_t hi = bits >> 16;
  float rem = x - __uint_as_float(bits & 0xFFFF0000u);
  uint32_t lo = __float_as_uint(rem) >> 16;
  return hi | (lo << 16);
}

// ---------------------------------------------------------------------------
// Fused K/V projection, 64-row tiles (512 blocks -> 2-3 blocks/CU).
// khl:  [B*N][256]  (hi,lo) interleaved along d (all 8 heads: 2*col)
// vthl: [B*H*16][2048] V transposed per head: row=(b*8+h)*16+d, el=2*n+part
// ---------------------------------------------------------------------------
__global__ __launch_bounds__(256, 3) void gemm_kv(
    const float* __restrict__ A, const float* __restrict__ Wk,
    const float* __restrict__ Wv, ushort_t* __restrict__ khl,
    ushort_t* __restrict__ vthl) {
  __shared__ float As[64][33];
  __shared__ float Wks[32][128];
  __shared__ float Wvs[32][128];
  const int tid = threadIdx.x;
  const size_t m0 = (size_t)blockIdx.x * 64;
  const int tr = tid >> 3, tc = tid & 7;
  const int r0 = tr * 2;
  const int c0 = tc * 16;

  float4 acck[2][4], accv[2][4];
#pragma unroll
  for (int j = 0; j < 2; ++j)
#pragma unroll
    for (int i = 0; i < 4; ++i) {
      acck[j][i] = make_float4(0.f, 0.f, 0.f, 0.f);
      accv[j][i] = make_float4(0.f, 0.f, 0.f, 0.f);
    }

  for (int kb = 0; kb < 4; ++kb) {
    __syncthreads();
    {
      int idx = tid;
#pragma unroll
      for (int it = 0; it < 2; ++it, idx += 256) {
        int r = idx >> 3, k4 = idx & 7;
        float4 v = reinterpret_cast<const float4*>(A + (m0 + r) * 128 + kb * 32)[k4];
        As[r][k4 * 4 + 0] = v.x; As[r][k4 * 4 + 1] = v.y;
        As[r][k4 * 4 + 2] = v.z; As[r][k4 * 4 + 3] = v.w;
      }
      idx = tid;
#pragma unroll
      for (int it = 0; it < 4; ++it, idx += 256) {
        int kk = idx >> 5, c4 = idx & 31;
        reinterpret_cast<float4*>(&Wks[kk][0])[c4] =
            reinterpret_cast<const float4*>(Wk + (size_t)(kb * 32 + kk) * 128)[c4];
      }
      idx = tid;
#pragma unroll
      for (int it = 0; it < 4; ++it, idx += 256) {
        int kk = idx >> 5, c4 = idx & 31;
        reinterpret_cast<float4*>(&Wvs[kk][0])[c4] =
            reinterpret_cast<const float4*>(Wv + (size_t)(kb * 32 + kk) * 128)[c4];
      }
    }
    __syncthreads();
#pragma unroll 8
    for (int kk = 0; kk < 32; ++kk) {
      float a0 = As[r0 + 0][kk], a1 = As[r0 + 1][kk];
      const float4* wkr = reinterpret_cast<const float4*>(&Wks[kk][c0]);
      const float4* wvr = reinterpret_cast<const float4*>(&Wvs[kk][c0]);
#pragma unroll
      for (int i = 0; i < 4; ++i) {
        float4 wk = wkr[i], wv = wvr[i];
        fma4(acck[0][i], a0, wk); fma4(acck[1][i], a1, wk);
        fma4(accv[0][i], a0, wv); fma4(accv[1][i], a1, wv);
      }
    }
  }

  // K epilogue: interleaved hi/lo bf16
#pragma unroll
  for (int j = 0; j < 2; ++j) {
    ushort_t* krow = khl + (m0 + r0 + j) * 256;
#pragma unroll
    for (int i = 0; i < 4; ++i) {
      uint4 pk;
      pk.x = f32_to_hl(acck[j][i].x);
      pk.y = f32_to_hl(acck[j][i].y);
      pk.z = f32_to_hl(acck[j][i].z);
      pk.w = f32_to_hl(acck[j][i].w);
      *reinterpret_cast<uint4*>(krow + 2 * (c0 + 4 * i)) = pk;
    }
  }
  // V epilogue: per-head transposed, interleaved hi/lo along n (2 n per store)
  const int bb = (int)(m0 >> 10);
  const int nbase = (int)(m0 & 1023) + r0;
#pragma unroll
  for (int i = 0; i < 4; ++i) {
#pragma unroll
    for (int e = 0; e < 4; ++e) {
      const int c = c0 + 4 * i + e;
      const int hh = c >> 4, dd = c & 15;
      uint2 pv;
      pv.x = f32_to_hl(reinterpret_cast<const float*>(&accv[0][i])[e]);
      pv.y = f32_to_hl(reinterpret_cast<const float*>(&accv[1][i])[e]);
      *reinterpret_cast<uint2*>(
          vthl + (size_t)((bb * H_ + hh) * 16 + dd) * 2048 + 2 * nbase) = pv;
    }
  }
}

// ---------------------------------------------------------------------------
// Q projection, 32-row tiles (512 blocks): q = [eln|load] @ Wq -> hl bf16
// ---------------------------------------------------------------------------
__global__ __launch_bounds__(256, 4) void gemm_q32(
    const float* __restrict__ A, const float* __restrict__ W,
    const float* __restrict__ ea, const float* __restrict__ ew,
    ushort_t* __restrict__ qhl) {
  __shared__ float As[32][33];
  __shared__ float Ws[32][128];
  const int tid = threadIdx.x;
  const size_t m0 = (size_t)blockIdx.x * 32;
  const int r0 = tid >> 3;
  const int c0 = (tid & 7) * 16;

  float4 acc[4];
#pragma unroll
  for (int i = 0; i < 4; ++i) acc[i] = make_float4(0.f, 0.f, 0.f, 0.f);

  for (int kb = 0; kb < 4; ++kb) {
    __syncthreads();
    {
      int r = tid >> 3, k4 = tid & 7;
      float4 v = reinterpret_cast<const float4*>(A + (m0 + r) * 128 + kb * 32)[k4];
      As[r][k4 * 4 + 0] = v.x; As[r][k4 * 4 + 1] = v.y;
      As[r][k4 * 4 + 2] = v.z; As[r][k4 * 4 + 3] = v.w;
      int idx = tid;
#pragma unroll
      for (int it = 0; it < 4; ++it, idx += 256) {
        int kk = idx >> 5, c4 = idx & 31;
        reinterpret_cast<float4*>(&Ws[kk][0])[c4] =
            reinterpret_cast<const float4*>(W + (size_t)(kb * 32 + kk) * 128)[c4];
      }
    }
    __syncthreads();
#pragma unroll 8
    for (int kk = 0; kk < 32; ++kk) {
      float a0 = As[r0][kk];
      const float4* wr = reinterpret_cast<const float4*>(&Ws[kk][c0]);
      fma4(acc[0], a0, wr[0]); fma4(acc[1], a0, wr[1]);
      fma4(acc[2], a0, wr[2]); fma4(acc[3], a0, wr[3]);
    }
  }
  {
    const float4* ew4 = reinterpret_cast<const float4*>(ew + c0);
    float av = ea[m0 + r0];
    fma4(acc[0], av, ew4[0]); fma4(acc[1], av, ew4[1]);
    fma4(acc[2], av, ew4[2]); fma4(acc[3], av, ew4[3]);
  }
  ushort_t* qrow = qhl + (m0 + r0) * 256;
#pragma unroll
  for (int i = 0; i < 4; ++i) {
    uint4 pq;
    pq.x = f32_to_hl(acc[i].x); pq.y = f32_to_hl(acc[i].y);
    pq.z = f32_to_hl(acc[i].z); pq.w = f32_to_hl(acc[i].w);
    *reinterpret_cast<uint4*>(qrow + 2 * (c0 + 4 * i)) = pq;
  }
}

// ---------------------------------------------------------------------------
// Wc projection, 32-row tiles (512 blocks): C = A @ W + bias (fp32)
// ---------------------------------------------------------------------------
__global__ __launch_bounds__(256, 4) void gemm_c32(
    const float* __restrict__ A, const float* __restrict__ W,
    const float* __restrict__ bias, float* __restrict__ C) {
  __shared__ float As[32][33];
  __shared__ float Ws[32][128];
  const int tid = threadIdx.x;
  const size_t m0 = (size_t)blockIdx.x * 32;
  const int r0 = tid >> 3;
  const int c0 = (tid & 7) * 16;

  float4 acc[4];
#pragma unroll
  for (int i = 0; i < 4; ++i) acc[i] = make_float4(0.f, 0.f, 0.f, 0.f);

  for (int kb = 0; kb < 4; ++kb) {
    __syncthreads();
    {
      int r = tid >> 3, k4 = tid & 7;
      float4 v = reinterpret_cast<const float4*>(A + (m0 + r) * 128 + kb * 32)[k4];
      As[r][k4 * 4 + 0] = v.x; As[r][k4 * 4 + 1] = v.y;
      As[r][k4 * 4 + 2] = v.z; As[r][k4 * 4 + 3] = v.w;
      int idx = tid;
#pragma unroll
      for (int it = 0; it < 4; ++it, idx += 256) {
        int kk = idx >> 5, c4 = idx & 31;
        reinterpret_cast<float4*>(&Ws[kk][0])[c4] =
            reinterpret_cast<const float4*>(W + (size_t)(kb * 32 + kk) * 128)[c4];
      }
    }
    __syncthreads();
#pragma unroll 8
    for (int kk = 0; kk < 32; ++kk) {
      float a0 = As[r0][kk];
      const float4* wr = reinterpret_cast<const float4*>(&Ws[kk][c0]);
      fma4(acc[0], a0, wr[0]); fma4(acc[1], a0, wr[1]);
      fma4(acc[2], a0, wr[2]); fma4(acc[3], a0, wr[3]);
    }
  }
  const float4* b4 = reinterpret_cast<const float4*>(bias + c0);
  float4* c4p = reinterpret_cast<float4*>(C + (m0 + r0) * 128 + c0);
#pragma unroll
  for (int i = 0; i < 4; ++i) {
    float4 bv = b4[i];
    float4 o = acc[i];
    o.x += bv.x; o.y += bv.y; o.z += bv.z; o.w += bv.w;
    c4p[i] = o;
  }
}

// ---------------------------------------------------------------------------
// Flash-decode MFMA attention pass: N split x2, ILP2 p-tiles per wave.
// Grid (8 = 4 ptiles x 2 nsplit, H, B), 4 waves. Writes unnormalized
// partials (o, m, l) per (ns, b, h, p).
// NOTE: launch_bounds min-waves=4 (NOT 8): forcing 8 caps VGPR at 32 and
// the ~52-VGPR body spills to scratch -> 408 MB/dispatch HBM writes (R6).
// ---------------------------------------------------------------------------
__global__ __launch_bounds__(256, 4) void attn_pass(
    const ushort_t* __restrict__ qhl, const ushort_t* __restrict__ khl,
    const ushort_t* __restrict__ vthl, const float* __restrict__ mask,
    float* __restrict__ pout, float* __restrict__ pml) {
  const int b = blockIdx.z, h = blockIdx.y;
  const int pt = blockIdx.x >> 1;
  const int ns = blockIdx.x & 1;
  const int tid = threadIdx.x;
  const int w = tid >> 6, lane = tid & 63;
  const int lp = lane & 15, g = lane >> 4;
  const int pA = pt * 128 + w * 16 + lp;
  const int pB = pA + 64;

  __shared__ __align__(16) ushort_t Ks[64 * 40];    // row stride 40 el (80 B)
  __shared__ __align__(16) ushort_t VTs[16 * 136];  // row stride 136 el (272 B)

  // Q fragments for both p-tiles: B1 = (qh,qh) pairs, B2 = (ql,0) pairs
  U8 qA1u, qA2u, qB1u, qB2u;
  {
    uint4 qldA = *reinterpret_cast<const uint4*>(
        qhl + (size_t)(b * P_ + pA) * 256 + h * 32 + g * 8);
    uint4 qldB = *reinterpret_cast<const uint4*>(
        qhl + (size_t)(b * P_ + pB) * 256 + h * 32 + g * 8);
    uint32_t a[4] = {qldA.x, qldA.y, qldA.z, qldA.w};
    uint32_t c[4] = {qldB.x, qldB.y, qldB.z, qldB.w};
#pragma unroll
    for (int i = 0; i < 4; ++i) {
      uint32_t lo16 = a[i] & 0xFFFFu;
      qA1u.u[i] = lo16 | (lo16 << 16);
      qA2u.u[i] = a[i] >> 16;
      uint32_t lo16b = c[i] & 0xFFFFu;
      qB1u.u[i] = lo16b | (lo16b << 16);
      qB2u.u[i] = c[i] >> 16;
    }
  }
  const short8 qA1 = qA1u.s8, qA2 = qA2u.s8, qB1 = qB1u.s8, qB2 = qB2u.s8;

  const float* mrowA = mask + (size_t)(b * P_ + pA) * N_;
  const float* mrowB = mask + (size_t)(b * P_ + pB) * N_;

  f32x4 accA = {0.f, 0.f, 0.f, 0.f}, accB = {0.f, 0.f, 0.f, 0.f};
  float mA = -1e30f, lA = 0.f, mB = -1e30f, lB = 0.f;

  for (int ch = 0; ch < 8; ++ch) {
    const int n0 = ns * 512 + ch * 64;
    __syncthreads();
    {
      const int n = tid >> 2, seg = tid & 3;
      uint4 kv = *reinterpret_cast<const uint4*>(
          khl + (size_t)(b * N_ + n0 + n) * 256 + h * 32 + seg * 8);
      *reinterpret_cast<uint4*>(Ks + n * 40 + seg * 8) = kv;
      const int d = tid >> 4, s2 = tid & 15;
      uint4 vv = *reinterpret_cast<const uint4*>(
          vthl + (size_t)((b * H_ + h) * 16 + d) * 2048 + n0 * 2 + s2 * 8);
      *reinterpret_cast<uint4*>(VTs + d * 136 + s2 * 8) = vv;
    }
    __syncthreads();

    // scores for both p-tiles; K fragment loaded once, used twice
    float svA[4][4], svB[4][4];
    float cmA = -1e30f, cmB = -1e30f;
#pragma unroll
    for (int tt = 0; tt < 4; ++tt) {
      short8 ka = *reinterpret_cast<const short8*>(Ks + (tt * 16 + lp) * 40 + g * 8);
      f32x4 aA = {0.f, 0.f, 0.f, 0.f};
      aA = __builtin_amdgcn_mfma_f32_16x16x32_bf16(ka, qA1, aA, 0, 0, 0);
      aA = __builtin_amdgcn_mfma_f32_16x16x32_bf16(ka, qA2, aA, 0, 0, 0);
      f32x4 aB = {0.f, 0.f, 0.f, 0.f};
      aB = __builtin_amdgcn_mfma_f32_16x16x32_bf16(ka, qB1, aB, 0, 0, 0);
      aB = __builtin_amdgcn_mfma_f32_16x16x32_bf16(ka, qB2, aB, 0, 0, 0);
      float4 mvA = *reinterpret_cast<const float4*>(mrowA + n0 + tt * 16 + g * 4);
      float4 mvB = *reinterpret_cast<const float4*>(mrowB + n0 + tt * 16 + g * 4);
      svA[tt][0] = fmaf(aA[0], 0.25f, mvA.x);
      svA[tt][1] = fmaf(aA[1], 0.25f, mvA.y);
      svA[tt][2] = fmaf(aA[2], 0.25f, mvA.z);
      svA[tt][3] = fmaf(aA[3], 0.25f, mvA.w);
      svB[tt][0] = fmaf(aB[0], 0.25f, mvB.x);
      svB[tt][1] = fmaf(aB[1], 0.25f, mvB.y);
      svB[tt][2] = fmaf(aB[2], 0.25f, mvB.z);
      svB[tt][3] = fmaf(aB[3], 0.25f, mvB.w);
      cmA = fmaxf(cmA, fmaxf(fmaxf(svA[tt][0], svA[tt][1]), fmaxf(svA[tt][2], svA[tt][3])));
      cmB = fmaxf(cmB, fmaxf(fmaxf(svB[tt][0], svB[tt][1]), fmaxf(svB[tt][2], svB[tt][3])));
    }
    cmA = fmaxf(cmA, __shfl_xor(cmA, 16));
    cmB = fmaxf(cmB, __shfl_xor(cmB, 16));
    cmA = fmaxf(cmA, __shfl_xor(cmA, 32));
    cmB = fmaxf(cmB, __shfl_xor(cmB, 32));
    const float nmA = fmaxf(mA, cmA), nmB = fmaxf(mB, cmB);
    const float fA = __expf(mA - nmA), fB = __expf(mB - nmB);
    accA[0] *= fA; accA[1] *= fA; accA[2] *= fA; accA[3] *= fA;
    accB[0] *= fB; accB[1] *= fB; accB[2] *= fB; accB[3] *= fB;
    float lsA = 0.f, lsB = 0.f;
#pragma unroll
    for (int tt = 0; tt < 4; ++tt)
#pragma unroll
      for (int r = 0; r < 4; ++r) {
        float eA = __expf(svA[tt][r] - nmA);
        float eB = __expf(svB[tt][r] - nmB);
        svA[tt][r] = eA; lsA += eA;
        svB[tt][r] = eB; lsB += eB;
      }
    lsA += __shfl_xor(lsA, 16); lsB += __shfl_xor(lsB, 16);
    lsA += __shfl_xor(lsA, 32); lsB += __shfl_xor(lsB, 32);
    lA = lA * fA + lsA; mA = nmA;
    lB = lB * fB + lsB; mB = nmB;

    // PV for both p-tiles; V fragment loaded once, used twice
#pragma unroll
    for (int tt = 0; tt < 4; ++tt) {
      U8 pA1, pA2, pB1, pB2;
#pragma unroll
      for (int r = 0; r < 4; ++r) {
        uint32_t ba = __float_as_uint(svA[tt][r]);
        uint32_t ha = ba >> 16;
        float rema = svA[tt][r] - __uint_as_float(ba & 0xFFFF0000u);
        pA1.u[r] = ha | (ha << 16);
        pA2.u[r] = __float_as_uint(rema) >> 16;
        uint32_t bb2 = __float_as_uint(svB[tt][r]);
        uint32_t hb = bb2 >> 16;
        float remb = svB[tt][r] - __uint_as_float(bb2 & 0xFFFF0000u);
        pB1.u[r] = hb | (hb << 16);
        pB2.u[r] = __float_as_uint(remb) >> 16;
      }
      short8 va = *reinterpret_cast<const short8*>(VTs + lp * 136 + tt * 32 + g * 8);
      accA = __builtin_amdgcn_mfma_f32_16x16x32_bf16(va, pA1.s8, accA, 0, 0, 0);
      accA = __builtin_amdgcn_mfma_f32_16x16x32_bf16(va, pA2.s8, accA, 0, 0, 0);
      accB = __builtin_amdgcn_mfma_f32_16x16x32_bf16(va, pB1.s8, accB, 0, 0, 0);
      accB = __builtin_amdgcn_mfma_f32_16x16x32_bf16(va, pB2.s8, accB, 0, 0, 0);
    }
  }

  // write unnormalized partials
  const size_t idxA = (size_t)(b * H_ + h) * P_ + pA;
  const size_t idxB = (size_t)(b * H_ + h) * P_ + pB;
  float4 oA, oB;
  oA.x = accA[0]; oA.y = accA[1]; oA.z = accA[2]; oA.w = accA[3];
  oB.x = accB[0]; oB.y = accB[1]; oB.z = accB[2]; oB.w = accB[3];
  *reinterpret_cast<float4*>(pout + ((size_t)ns * BHP_ + idxA) * 16 + g * 4) = oA;
  *reinterpret_cast<float4*>(pout + ((size_t)ns * BHP_ + idxB) * 16 + g * 4) = oB;
  if (g == 0) {
    reinterpret_cast<float2*>(pml)[(size_t)ns * BHP_ + idxA] = make_float2(mA, lA);
    reinterpret_cast<float2*>(pml)[(size_t)ns * BHP_ + idxB] = make_float2(mB, lB);
  }
}

// ---------------------------------------------------------------------------
// Combine 2 partials -> normalized attention output in [B,P,H*D] layout.
// ---------------------------------------------------------------------------
__global__ __launch_bounds__(256, 8) void attn_combine(
    const float* __restrict__ pout, const float* __restrict__ pml,
    float* __restrict__ O) {
  const int idx = blockIdx.x * 256 + threadIdx.x;   // over B*H*P
  const int b = idx >> 12;
  const int h = (idx >> 9) & 7;
  const int p = idx & 511;
  float2 ml0 = reinterpret_cast<const float2*>(pml)[idx];
  float2 ml1 = reinterpret_cast<const float2*>(pml)[BHP_ + idx];
  const float M = fmaxf(ml0.x, ml1.x);
  const float w0 = __expf(ml0.x - M), w1 = __expf(ml1.x - M);
  const float inv = 1.f / (ml0.y * w0 + ml1.y * w1);
  const float4* p0 = reinterpret_cast<const float4*>(pout + (size_t)idx * 16);
  const float4* p1 = reinterpret_cast<const float4*>(pout + ((size_t)BHP_ + idx) * 16);
  float4* o4 = reinterpret_cast<float4*>(O + (size_t)(b * P_ + p) * E_ + h * 16);
#pragma unroll
  for (int i = 0; i < 4; ++i) {
    float4 a = p0[i], c = p1[i];
    float4 o;
    o.x = (a.x * w0 + c.x * w1) * inv;
    o.y = (a.y * w0 + c.y * w1) * inv;
    o.z = (a.z * w0 + c.z * w1) * inv;
    o.w = (a.w * w0 + c.w * w1) * inv;
    o4[i] = o;
  }
}

// ---------------------------------------------------------------------------
// MFMA logits: T[b,p,n] = 10*tanh((mh[b,p,:]·enc[b,n,:])/sqrt(128)) + mask
// Grid (4 n-quarters, 8 p-tiles, B). Block 256 = 4 waves x 16 p.
// ---------------------------------------------------------------------------
__global__ __launch_bounds__(256, 4) void logits_mfma(
    const float* __restrict__ mh, const float* __restrict__ enc,
    const float* __restrict__ mask, float* __restrict__ T) {
  const int b = blockIdx.z;
  const int p0 = blockIdx.y * 64;
  const int nq = blockIdx.x;           // n quarter: 256 cols
  const int tid = threadIdx.x;
  const int w = tid >> 6, lane = tid & 63;
  const int lp = lane & 15, g = lane >> 4;
  const int p = p0 + w * 16 + lp;

  __shared__ __align__(16) ushort_t Es[64 * 264];   // 64 enc rows, hl

  // B fragments: this lane's mh row, 8 k-windows of 16
  U8 fb1[8], fb2[8];
  {
    const float* mrow_mh = mh + (size_t)(b * P_ + p) * E_;
#pragma unroll
    for (int win = 0; win < 8; ++win) {
      float4 v = *reinterpret_cast<const float4*>(mrow_mh + win * 16 + g * 4);
      float vv[4] = {v.x, v.y, v.z, v.w};
#pragma unroll
      for (int r = 0; r < 4; ++r) {
        uint32_t bits = __float_as_uint(vv[r]);
        uint32_t hh = bits >> 16;
        float rem = vv[r] - __uint_as_float(bits & 0xFFFF0000u);
        fb1[win].u[r] = hh | (hh << 16);
        fb2[win].u[r] = __float_as_uint(rem) >> 16;
      }
    }
  }

  const float* mrow = mask + (size_t)(b * P_ + p) * N_ + nq * 256;
  float* trow = T + (size_t)(b * P_ + p) * N_ + nq * 256;
  const float inv_s = 0.08838834764831845f;  // 1/sqrt(128)

  for (int ch = 0; ch < 4; ++ch) {           // 64 n per chunk
    const int n0g = nq * 256 + ch * 64;
    __syncthreads();
    {
      int idx = tid;
#pragma unroll
      for (int it = 0; it < 8; ++it, idx += 256) {
        const int r = idx >> 5, f4 = idx & 31;
        float4 v = *reinterpret_cast<const float4*>(
            enc + ((size_t)b * N_ + n0g + r) * E_ + f4 * 4);
        uint4 o;
        o.x = f32_to_hl(v.x); o.y = f32_to_hl(v.y);
        o.z = f32_to_hl(v.z); o.w = f32_to_hl(v.w);
        *reinterpret_cast<uint4*>(Es + r * 264 + f4 * 8) = o;
      }
    }
    __syncthreads();

#pragma unroll
    for (int tt = 0; tt < 4; ++tt) {
      f32x4 acc = {0.f, 0.f, 0.f, 0.f};
#pragma unroll
      for (int win = 0; win < 8; ++win) {
        short8 ea = *reinterpret_cast<const short8*>(
            Es + (tt * 16 + lp) * 264 + win * 32 + g * 8);
        acc = __builtin_amdgcn_mfma_f32_16x16x32_bf16(ea, fb1[win].s8, acc, 0, 0, 0);
        acc = __builtin_amdgcn_mfma_f32_16x16x32_bf16(ea, fb2[win].s8, acc, 0, 0, 0);
      }
      float4 mv = *reinterpret_cast<const float4*>(mrow + ch * 64 + tt * 16 + g * 4);
      float4 o;
      o.x = fmaf(10.f, fast_tanh(acc[0] * inv_s), mv.x);
      o.y = fmaf(10.f, fast_tanh(acc[1] * inv_s), mv.y);
      o.z = fmaf(10.f, fast_tanh(acc[2] * inv_s), mv.z);
      o.w = fmaf(10.f, fast_tanh(acc[3] * inv_s), mv.w);
      *reinterpret_cast<float4*>(trow + ch * 64 + tt * 16 + g * 4) = o;
    }
  }
}

// ---------------------------------------------------------------------------
// probs[row,:] = softmax(T[row,:] * 10)
// ---------------------------------------------------------------------------
__global__ __launch_bounds__(256, 4) void softmax_rows(
    const float* __restrict__ T, float* __restrict__ O) {
  const size_t row = blockIdx.x;
  const int tid = threadIdx.x;
  const float4 v = reinterpret_cast<const float4*>(T + row * N_)[tid];
  float lm = fmaxf(fmaxf(v.x, v.y), fmaxf(v.z, v.w));
#pragma unroll
  for (int o = 32; o; o >>= 1) lm = fmaxf(lm, __shfl_xor(lm, o));
  __shared__ float red[8];
  const int wave = tid >> 6, lane = tid & 63;
  if (lane == 0) red[wave] = lm;
  __syncthreads();
  const float m = fmaxf(fmaxf(red[0], red[1]), fmaxf(red[2], red[3]));
  float4 w;
  w.x = __expf((v.x - m) * 10.f);
  w.y = __expf((v.y - m) * 10.f);
  w.z = __expf((v.z - m) * 10.f);
  w.w = __expf((v.w - m) * 10.f);
  float ls = w.x + w.y + w.z + w.w;
#pragma unroll
  for (int o = 32; o; o >>= 1) ls += __shfl_xor(ls, o);
  if (lane == 0) red[4 + wave] = ls;
  __syncthreads();
  const float inv = 1.f / (red[4] + red[5] + red[6] + red[7]);
  float4 o4;
  o4.x = w.x * inv; o4.y = w.y * inv; o4.z = w.z * inv; o4.w = w.w * inv;
  reinterpret_cast<float4*>(O + row * N_)[tid] = o4;
}

extern "C" void kernel_launch(void* const* d_in, const int* in_sizes, int n_in,
                              void* d_out, int out_size, void* d_ws, size_t ws_size,
                              hipStream_t stream) {
  const float* eln  = (const float*)d_in[0];
  const float* load = (const float*)d_in[1];
  const float* mask = (const float*)d_in[2];
  const float* enc  = (const float*)d_in[3];
  const float* Wq   = (const float*)d_in[4];
  const float* Wk   = (const float*)d_in[5];
  const float* Wv   = (const float*)d_in[6];
  const float* Wc   = (const float*)d_in[7];
  const float* bc   = (const float*)d_in[8];
  float* out = (float*)d_out;

  // Workspace layout (bytes):
  //   khl  : 16.78 MB   vthl : 16.78 MB   qhl/mhbuf : 8.39 MB
  //   tbuf : 67.11 MB  -- internally: abuf (8.39) | pout2 (16.78) | pml2 (2.1)
  char* base = (char*)d_ws;
  ushort_t* khl  = (ushort_t*)base;
  ushort_t* vthl = (ushort_t*)(base + 16777216);
  ushort_t* qhl  = (ushort_t*)(base + 2 * 16777216);
  float* mhbuf   = (float*)(base + 2 * 16777216);            // overlaps qhl
  float* tbuf    = (float*)(base + 2 * 16777216 + 8388608);
  float* abuf    = tbuf;                                     // dead before logits
  float* pout    = (float*)((char*)tbuf + 8388608);
  float* pml     = (float*)((char*)tbuf + 8388608 + 16777216);

  // K|V projections -> bf16 hi/lo (+ V transpose)
  gemm_kv<<<dim3(512), 256, 0, stream>>>(enc, Wk, Wv, khl, vthl);
  // q = [eln | load] @ Wq_last -> bf16 hi/lo
  gemm_q32<<<dim3(512), 256, 0, stream>>>(eln, Wq, load, Wq + 128 * 128, qhl);
  // flash-decode MFMA attention (N-split x2, ILP2) + combine
  attn_pass<<<dim3(8, H_, B_), 256, 0, stream>>>(qhl, khl, vthl, mask, pout, pml);
  attn_combine<<<dim3(BHP_ / 256), 256, 0, stream>>>(pout, pml, abuf);
  // mh = attn_out @ Wc + bc
  gemm_c32<<<dim3(512), 256, 0, stream>>>(abuf, Wc, bc, mhbuf);
  // logits = 10*tanh(mh·encT/sqrt(128)) + mask
  logits_mfma<<<dim3(4, 8, B_), 256, 0, stream>>>(mhbuf, enc, mask, tbuf);
  // probs = softmax(logits/0.1)
  softmax_rows<<<dim3(16384), 256, 0, stream>>>(tbuf, out);
}